// Round 7
// baseline (89.872 us; speedup 1.0000x reference)
//
#include <hip/hip_runtime.h>
#include <hip/hip_bf16.h>

#define FDIM 128
#define NLEV 4
#define NT   64   // nodes per transform block
#define WPAD 136  // padded row stride (u16) for LDS tiles: 272B -> 2-way bank alias (free)

typedef unsigned int  u32;
typedef unsigned short u16;

typedef __attribute__((ext_vector_type(8))) short short8v;  // 8 bf16 (4 VGPRs)
typedef __attribute__((ext_vector_type(4))) float f32x4;

__device__ __forceinline__ float bf_lo(u32 p) { return __uint_as_float(p << 16); }
__device__ __forceinline__ float bf_hi(u32 p) { return __uint_as_float(p & 0xffff0000u); }
__device__ __forceinline__ u16 f2bf(float f) {
    u32 u = __float_as_uint(f);
    u32 r = (u + 0x7fffu + ((u >> 16) & 1u)) >> 16;   // round-nearest-even
    return (u16)r;
}
__device__ __forceinline__ u32 pack2(float a, float b) {
    return (u32)f2bf(a) | ((u32)f2bf(b) << 16);
}

// ---- K0: fast zero (grid-stride int4) ----
__global__ __launch_bounds__(256) void zero_kernel(int4* __restrict__ p, int n4) {
    int i = blockIdx.x * 256 + threadIdx.x;
    int stride = gridDim.x * 256;
    for (; i < n4; i += stride) p[i] = make_int4(0, 0, 0, 0);
}

// ---- K1: fused node-binning (first nodeBlocks blocks) + edge histogram (all blocks) ----
__global__ __launch_bounds__(256) void binhist_kernel(
    const int* __restrict__ lv, int* __restrict__ cnt, int* __restrict__ bin,
    const int2* __restrict__ edges2, int* __restrict__ deg,
    int N, int E, int nodeBlocks)
{
    int t = threadIdx.x;
    int b = blockIdx.x;

    int e = b * 256 + t;
    if (e < E) {
        int2 eg = edges2[e];
        if (lv[eg.y] > lv[eg.x]) atomicAdd(&deg[eg.y], 1);  // valid <=> lv[hi] > lv[lo]
    }

    if (b < nodeBlocks) {
        __shared__ int lcnt[NLEV];
        __shared__ int lbase[NLEV];
        if (t < NLEV) lcnt[t] = 0;
        __syncthreads();
        int n = b * 256 + t;
        int l = -1, pos = 0;
        if (n < N) {
            l = lv[n];
            if (l >= 0 && l < NLEV) pos = atomicAdd(&lcnt[l], 1);
            else l = -1;
        }
        __syncthreads();
        if (t < NLEV) lbase[t] = lcnt[t] ? atomicAdd(&cnt[t], lcnt[t]) : 0;
        __syncthreads();
        if (l >= 0) bin[l * N + lbase[l] + pos] = n;
    }
}

// ---- K2: per-1024-chunk local exclusive scan; LAST block exclusive-scans bsum in place ----
__global__ __launch_bounds__(256) void scan_local(const int* __restrict__ deg,
                                                  int* __restrict__ rowstart,
                                                  int* __restrict__ bsum,
                                                  int* __restrict__ done, int N) {
    __shared__ int part[256];
    __shared__ int iamlast;
    int t = threadIdx.x;
    int nb = gridDim.x;
    int base = blockIdx.x * 1024 + t * 4;
    int v[4];
    #pragma unroll
    for (int k = 0; k < 4; ++k) v[k] = (base + k < N) ? deg[base + k] : 0;
    int s = v[0] + v[1] + v[2] + v[3];
    part[t] = s;
    __syncthreads();
    for (int off = 1; off < 256; off <<= 1) {      // Hillis-Steele inclusive
        int x = (t >= off) ? part[t - off] : 0;
        __syncthreads();
        part[t] += x;
        __syncthreads();
    }
    if (t == 255) bsum[blockIdx.x] = part[255];    // raw chunk total
    int run = part[t] - s;
    #pragma unroll
    for (int k = 0; k < 4; ++k) {
        if (base + k < N) rowstart[base + k] = run;
        run += v[k];
    }

    // last-finishing block converts bsum raw totals -> exclusive prefix
    __threadfence();
    __syncthreads();
    if (t == 0) iamlast = (atomicAdd(done, 1) == nb - 1) ? 1 : 0;
    __syncthreads();
    if (iamlast) {
        __threadfence();
        int val = (t < nb) ? ((volatile int*)bsum)[t] : 0;
        part[t] = val;
        __syncthreads();
        for (int off = 1; off < 256; off <<= 1) {
            int x = (t >= off) ? part[t - off] : 0;
            __syncthreads();
            part[t] += x;
            __syncthreads();
        }
        if (t < nb) bsum[t] = part[t] - val;       // exclusive
    }
}

// ---- K3 fused: transform tiles (blocks < transBlocks) | csr fill (rest) ----
__global__ __launch_bounds__(256) void transform_fill_kernel(
    const float* __restrict__ X, const float* __restrict__ Wg,
    const float* __restrict__ bg, const int* __restrict__ cnt,
    const int* __restrict__ bin, u16* __restrict__ Y,
    const int2* __restrict__ edges2, const int* __restrict__ lv,
    const int* __restrict__ rowstart, const int* __restrict__ bsum,
    int* __restrict__ ncur, int* __restrict__ csr,
    int N, int E, int blocksPerLevel, int transBlocks)
{
    int t = threadIdx.x;
    int b = blockIdx.x;

    if (b >= transBlocks) {
        // ---- fill role: csr[rs(hi) + ncur[hi]++] = lo ----
        int e = (b - transBlocks) * 256 + t;
        if (e < E) {
            int2 eg = edges2[e];
            int lo = eg.x, hi = eg.y;
            if (lv[hi] > lv[lo]) {
                int s = rowstart[hi] + bsum[hi >> 10] + atomicAdd(&ncur[hi], 1);
                csr[s] = lo;
            }
        }
        return;
    }

    // ---- transform role: Y[n] = bf16(0.2*(X[n] @ W[l].T + b[l])) ----
    __shared__ __align__(16) u16 Wt[FDIM][WPAD];  // W[l] bf16 row-major, padded
    __shared__ __align__(16) u16 Ot[NT][WPAD];    // output staging
    __shared__ int nodes_s[NT];

    int l     = b / blocksPerLevel;
    int chunk = b % blocksPerLevel;
    int m_total = cnt[l];
    int base = chunk * NT;
    if (base >= m_total) return;
    int m = min(NT, m_total - base);

    if (t < NT) nodes_s[t] = (t < m) ? bin[l * N + base + t] : -1;

    const float4* Wl4 = (const float4*)(Wg + (size_t)l * FDIM * FDIM);
    #pragma unroll
    for (int k = 0; k < 16; ++k) {
        int flat4 = t + k * 256;
        int row = flat4 >> 5;
        int c4  = flat4 & 31;
        float4 v = Wl4[flat4];
        *(uint2*)&Wt[row][c4 * 4] = make_uint2(pack2(v.x, v.y), pack2(v.z, v.w));
    }
    __syncthreads();

    int wid  = t >> 6;
    int lane = t & 63;
    int arow = lane & 15;
    int kgrp = lane >> 4;

    int node = nodes_s[wid * 16 + arow];
    const float* xrow = X + (size_t)(node < 0 ? 0 : node) * FDIM;

    f32x4 acc[8];
    #pragma unroll
    for (int ft = 0; ft < 8; ++ft) acc[ft] = (f32x4){0.f, 0.f, 0.f, 0.f};

    #pragma unroll
    for (int kstep = 0; kstep < 4; ++kstep) {
        int k0 = kstep * 32 + kgrp * 8;
        union { u32 u[4]; short8v v; } au;
        if (node >= 0) {
            float4 x0 = *(const float4*)&xrow[k0];
            float4 x1 = *(const float4*)&xrow[k0 + 4];
            au.u[0] = pack2(x0.x, x0.y); au.u[1] = pack2(x0.z, x0.w);
            au.u[2] = pack2(x1.x, x1.y); au.u[3] = pack2(x1.z, x1.w);
        } else {
            au.u[0] = au.u[1] = au.u[2] = au.u[3] = 0;
        }
        #pragma unroll
        for (int ft = 0; ft < 8; ++ft) {
            short8v bb = *(const short8v*)&Wt[ft * 16 + arow][k0];
            acc[ft] = __builtin_amdgcn_mfma_f32_16x16x32_bf16(au.v, bb, acc[ft], 0, 0, 0);
        }
    }

    const float* bl = bg + l * FDIM;
    #pragma unroll
    for (int ft = 0; ft < 8; ++ft) {
        float bv = bl[ft * 16 + arow];
        #pragma unroll
        for (int reg = 0; reg < 4; ++reg) {
            int r = wid * 16 + kgrp * 4 + reg;       // this wave's own rows only
            Ot[r][ft * 16 + arow] = f2bf(0.2f * (acc[ft][reg] + bv));
        }
    }
    __syncthreads();

    #pragma unroll
    for (int k = 0; k < 4; ++k) {
        int flat16 = t + k * 256;
        int row = flat16 >> 4;
        int c   = flat16 & 15;
        int nd = nodes_s[row];
        if (nd >= 0)
            *(uint4*)&Y[(size_t)nd * FDIM + c * 8] = *(const uint4*)&Ot[row][c * 8];
    }
}

// ---- K4: gather. Half-wave (32 lanes) per node; batch-4 Y loads for MLP ----
__global__ __launch_bounds__(256) void gather_kernel(
    const float* __restrict__ X, const uint2* __restrict__ Yp,
    const int* __restrict__ rowstart, const int* __restrict__ bsum,
    const int* __restrict__ deg, const int* __restrict__ csr,
    float* __restrict__ out, int N)
{
    int wid  = threadIdx.x >> 6;
    int lane = threadIdx.x & 63;
    int hl = lane >> 5;          // half: 0 or 1
    int sl = lane & 31;          // sub-lane within half
    int node = blockIdx.x * 8 + wid * 2 + hl;
    if (node >= N) return;

    float4 xv = *(const float4*)&X[(size_t)node * FDIM + sl * 4];
    int row = rowstart[node] + bsum[node >> 10];
    int d   = deg[node];

    float a0 = 0.f, a1 = 0.f, a2 = 0.f, a3 = 0.f;
    for (int base = 0; base < d; base += 32) {
        int c = min(32, d - base);
        int myLo = (sl < c) ? csr[row + base + sl] : 0;
        for (int i = 0; i < c; i += 4) {
            int b = min(4, c - i);
            uint2 p[4];
            #pragma unroll
            for (int j = 0; j < 4; ++j) {
                if (j < b) {
                    int lo = __shfl(myLo, hl * 32 + i + j, 64);
                    p[j] = Yp[(size_t)lo * (FDIM / 4) + sl];   // 8B/lane, 256B/edge
                }
            }
            #pragma unroll
            for (int j = 0; j < 4; ++j) {
                if (j < b) {
                    a0 += bf_lo(p[j].x); a1 += bf_hi(p[j].x);
                    a2 += bf_lo(p[j].y); a3 += bf_hi(p[j].y);
                }
            }
        }
    }
    float4 o = make_float4(xv.x + a0, xv.y + a1, xv.z + a2, xv.w + a3);
    *(float4*)&out[(size_t)node * FDIM + sl * 4] = o;
}

extern "C" void kernel_launch(void* const* d_in, const int* in_sizes, int n_in,
                              void* d_out, int out_size, void* d_ws, size_t ws_size,
                              hipStream_t stream) {
    const float* X  = (const float*)d_in[0];
    const float* Wg = (const float*)d_in[1];
    const float* bg = (const float*)d_in[2];
    const int*   lv = (const int*)d_in[3];
    const int*   eg = (const int*)d_in[4];
    float* out = (float*)d_out;

    int N = in_sizes[3];
    int E = in_sizes[4] / 2;

    // workspace: Y (bf16 N*F) | cnt(16: 0-3 level counts, 8 = scan done flag)
    //            deg(N) ncur(N) [zeroed with cnt] | rowstart(N) | bsum(128) | bin(4N) | csr(E)
    char* p = (char*)d_ws;
    u16* Y        = (u16*)p;            p += (size_t)N * FDIM * sizeof(u16);
    int* cnt      = (int*)p;            p += 16 * sizeof(int);
    int* deg      = (int*)p;            p += (size_t)N * sizeof(int);
    int* ncur     = (int*)p;            p += (size_t)N * sizeof(int);
    int* rowstart = (int*)p;            p += (size_t)N * sizeof(int);
    int* bsum     = (int*)p;            p += 128 * sizeof(int);
    int* bin      = (int*)p;            p += (size_t)4 * N * sizeof(int);
    int* csr      = (int*)p;
    int* done     = cnt + 8;

    int nzero4 = (2 * N + 16) / 4;
    zero_kernel<<<(nzero4 + 255) / 256, 256, 0, stream>>>((int4*)cnt, nzero4);

    int nodeBlocks = (N + 255) / 256;
    int edgeBlocks = (E + 255) / 256;
    binhist_kernel<<<max(nodeBlocks, edgeBlocks), 256, 0, stream>>>(
        lv, cnt, bin, (const int2*)eg, deg, N, E, nodeBlocks);

    int nb = (N + 1023) / 1024;   // <= 128 for N <= 131072
    scan_local<<<nb, 256, 0, stream>>>(deg, rowstart, bsum, done, N);

    int blocksPerLevel = (N + NT - 1) / NT;
    int transBlocks = NLEV * blocksPerLevel;
    transform_fill_kernel<<<transBlocks + edgeBlocks, 256, 0, stream>>>(
        X, Wg, bg, cnt, bin, Y, (const int2*)eg, lv, rowstart, bsum, ncur, csr,
        N, E, blocksPerLevel, transBlocks);

    gather_kernel<<<(N + 7) / 8, 256, 0, stream>>>(
        X, (const uint2*)Y, rowstart, bsum, deg, csr, out, N);
}

// Round 8
// 80.920 us; speedup vs baseline: 1.1106x; 1.1106x over previous
//
#include <hip/hip_runtime.h>
#include <hip/hip_bf16.h>

#define FDIM 128
#define NLEV 4
#define NT   64     // nodes per transform block
#define WPAD 136    // padded row stride (u16): 272B -> 2-way bank alias (free)
#define SLOTS 8     // ELL width; deg>SLOTS goes to overflow list
#define OVFCAP 65536

typedef unsigned int  u32;
typedef unsigned short u16;

typedef __attribute__((ext_vector_type(8))) short short8v;  // 8 bf16 (4 VGPRs)
typedef __attribute__((ext_vector_type(4))) float f32x4;

__device__ __forceinline__ float bf_lo(u32 p) { return __uint_as_float(p << 16); }
__device__ __forceinline__ float bf_hi(u32 p) { return __uint_as_float(p & 0xffff0000u); }
__device__ __forceinline__ u16 f2bf(float f) {
    u32 u = __float_as_uint(f);
    u32 r = (u + 0x7fffu + ((u >> 16) & 1u)) >> 16;   // round-nearest-even
    return (u16)r;
}
__device__ __forceinline__ u32 pack2(float a, float b) {
    return (u32)f2bf(a) | ((u32)f2bf(b) << 16);
}

// ---- K0: fast zero (grid-stride int4) ----
__global__ __launch_bounds__(256) void zero_kernel(int4* __restrict__ p, int n4) {
    int i = blockIdx.x * 256 + threadIdx.x;
    int stride = gridDim.x * 256;
    for (; i < n4; i += stride) p[i] = make_int4(0, 0, 0, 0);
}

// ---- K1: single edge pass builds ELL directly (deg doubles as slot cursor),
//          plus node-binning role on the first nodeBlocks blocks ----
__global__ __launch_bounds__(256) void fillbin_kernel(
    const int* __restrict__ lv, int* __restrict__ cnt, int* __restrict__ bin,
    const int2* __restrict__ edges2, int* __restrict__ deg, int* __restrict__ ell,
    int2* __restrict__ ovf, int* __restrict__ ovfcnt,
    int N, int E, int nodeBlocks)
{
    int t = threadIdx.x;
    int b = blockIdx.x;

    int e = b * 256 + t;
    if (e < E) {
        int2 ed = edges2[e];
        int lo = ed.x, hi = ed.y;
        if (lv[hi] > lv[lo]) {                     // valid <=> lv[hi] > lv[lo]
            int slot = atomicAdd(&deg[hi], 1);
            if (slot < SLOTS) ell[hi * SLOTS + slot] = lo;
            else {
                int oi = atomicAdd(ovfcnt, 1);
                if (oi < OVFCAP) ovf[oi] = make_int2(lo, hi);
            }
        }
    }

    if (b < nodeBlocks) {
        __shared__ int lcnt[NLEV];
        __shared__ int lbase[NLEV];
        if (t < NLEV) lcnt[t] = 0;
        __syncthreads();
        int n = b * 256 + t;
        int l = -1, pos = 0;
        if (n < N) {
            l = lv[n];
            if (l >= 0 && l < NLEV) pos = atomicAdd(&lcnt[l], 1);
            else l = -1;
        }
        __syncthreads();
        if (t < NLEV) lbase[t] = lcnt[t] ? atomicAdd(&cnt[t], lcnt[t]) : 0;
        __syncthreads();
        if (l >= 0) bin[l * N + lbase[l] + pos] = n;
    }
}

// ---- K2 (MFMA): Y[n] = bf16( 0.2*(X[n] @ W[l].T + b[l]) ) for binned nodes ----
__global__ __launch_bounds__(256) void transform_kernel(
    const float* __restrict__ X, const float* __restrict__ Wg,
    const float* __restrict__ bg, const int* __restrict__ cnt,
    const int* __restrict__ bin, u16* __restrict__ Y, int N, int blocksPerLevel)
{
    __shared__ __align__(16) u16 Wt[FDIM][WPAD];  // W[l] bf16 row-major, padded
    __shared__ __align__(16) u16 Ot[NT][WPAD];    // output staging
    __shared__ int nodes_s[NT];

    int b = blockIdx.x;
    int l     = b / blocksPerLevel;
    int chunk = b % blocksPerLevel;
    int m_total = cnt[l];
    int base = chunk * NT;
    if (base >= m_total) return;
    int m = min(NT, m_total - base);
    int t = threadIdx.x;

    if (t < NT) nodes_s[t] = (t < m) ? bin[l * N + base + t] : -1;

    const float4* Wl4 = (const float4*)(Wg + (size_t)l * FDIM * FDIM);
    #pragma unroll
    for (int k = 0; k < 16; ++k) {
        int flat4 = t + k * 256;
        int row = flat4 >> 5;
        int c4  = flat4 & 31;
        float4 v = Wl4[flat4];
        *(uint2*)&Wt[row][c4 * 4] = make_uint2(pack2(v.x, v.y), pack2(v.z, v.w));
    }
    __syncthreads();

    int wid  = t >> 6;
    int lane = t & 63;
    int arow = lane & 15;
    int kgrp = lane >> 4;

    int node = nodes_s[wid * 16 + arow];
    const float* xrow = X + (size_t)(node < 0 ? 0 : node) * FDIM;

    f32x4 acc[8];
    #pragma unroll
    for (int ft = 0; ft < 8; ++ft) acc[ft] = (f32x4){0.f, 0.f, 0.f, 0.f};

    #pragma unroll
    for (int kstep = 0; kstep < 4; ++kstep) {
        int k0 = kstep * 32 + kgrp * 8;
        union { u32 u[4]; short8v v; } au;
        if (node >= 0) {
            float4 x0 = *(const float4*)&xrow[k0];
            float4 x1 = *(const float4*)&xrow[k0 + 4];
            au.u[0] = pack2(x0.x, x0.y); au.u[1] = pack2(x0.z, x0.w);
            au.u[2] = pack2(x1.x, x1.y); au.u[3] = pack2(x1.z, x1.w);
        } else {
            au.u[0] = au.u[1] = au.u[2] = au.u[3] = 0;
        }
        #pragma unroll
        for (int ft = 0; ft < 8; ++ft) {
            short8v bb = *(const short8v*)&Wt[ft * 16 + arow][k0];
            acc[ft] = __builtin_amdgcn_mfma_f32_16x16x32_bf16(au.v, bb, acc[ft], 0, 0, 0);
        }
    }

    const float* bl = bg + l * FDIM;
    #pragma unroll
    for (int ft = 0; ft < 8; ++ft) {
        float bv = bl[ft * 16 + arow];
        #pragma unroll
        for (int reg = 0; reg < 4; ++reg) {
            int r = wid * 16 + kgrp * 4 + reg;       // this wave's own rows only
            Ot[r][ft * 16 + arow] = f2bf(0.2f * (acc[ft][reg] + bv));
        }
    }
    __syncthreads();

    #pragma unroll
    for (int k = 0; k < 4; ++k) {
        int flat16 = t + k * 256;
        int row = flat16 >> 4;
        int c   = flat16 & 15;
        int nd = nodes_s[row];
        if (nd >= 0)
            *(uint4*)&Y[(size_t)nd * FDIM + c * 8] = *(const uint4*)&Ot[row][c * 8];
    }
}

// ---- K3: gather from ELL. Half-wave per node; batch-4 Y loads for MLP ----
__global__ __launch_bounds__(256) void gather_kernel(
    const float* __restrict__ X, const uint2* __restrict__ Yp,
    const int* __restrict__ deg, const int* __restrict__ ell,
    float* __restrict__ out, int N)
{
    int wid  = threadIdx.x >> 6;
    int lane = threadIdx.x & 63;
    int hl = lane >> 5;          // half: 0 or 1
    int sl = lane & 31;          // sub-lane within half
    int node = blockIdx.x * 8 + wid * 2 + hl;
    if (node >= N) return;

    float4 xv = *(const float4*)&X[(size_t)node * FDIM + sl * 4];
    int d = deg[node];
    if (d > SLOTS) d = SLOTS;
    int myLo = (sl < d) ? ell[node * SLOTS + sl] : 0;

    float a0 = 0.f, a1 = 0.f, a2 = 0.f, a3 = 0.f;
    for (int i = 0; i < d; i += 4) {
        int bcnt = min(4, d - i);
        uint2 p[4];
        #pragma unroll
        for (int j = 0; j < 4; ++j) {
            if (j < bcnt) {
                int lo = __shfl(myLo, hl * 32 + i + j, 64);
                p[j] = Yp[(size_t)lo * (FDIM / 4) + sl];   // 8B/lane, 256B/edge
            }
        }
        #pragma unroll
        for (int j = 0; j < 4; ++j) {
            if (j < bcnt) {
                a0 += bf_lo(p[j].x); a1 += bf_hi(p[j].x);
                a2 += bf_lo(p[j].y); a3 += bf_hi(p[j].y);
            }
        }
    }
    float4 o = make_float4(xv.x + a0, xv.y + a1, xv.z + a2, xv.w + a3);
    *(float4*)&out[(size_t)node * FDIM + sl * 4] = o;
}

// ---- K4: replay overflow edges (deg > SLOTS) with f32 atomics; tiny count ----
__global__ __launch_bounds__(256) void ovf_kernel(
    const int2* __restrict__ ovf, const int* __restrict__ ovfcnt,
    const uint2* __restrict__ Yp, float* __restrict__ out)
{
    int cnt = *ovfcnt;
    if (cnt > OVFCAP) cnt = OVFCAP;
    int hw  = (blockIdx.x * 256 + threadIdx.x) >> 5;   // global half-wave id
    int sl  = threadIdx.x & 31;
    int nhw = gridDim.x * 8;
    for (int i = hw; i < cnt; i += nhw) {
        int2 ed = ovf[i];
        uint2 pv = Yp[(size_t)ed.x * (FDIM / 4) + sl];
        float* dst = out + (size_t)ed.y * FDIM + sl * 4;
        atomicAdd(dst + 0, bf_lo(pv.x));
        atomicAdd(dst + 1, bf_hi(pv.x));
        atomicAdd(dst + 2, bf_lo(pv.y));
        atomicAdd(dst + 3, bf_hi(pv.y));
    }
}

extern "C" void kernel_launch(void* const* d_in, const int* in_sizes, int n_in,
                              void* d_out, int out_size, void* d_ws, size_t ws_size,
                              hipStream_t stream) {
    const float* X  = (const float*)d_in[0];
    const float* Wg = (const float*)d_in[1];
    const float* bg = (const float*)d_in[2];
    const int*   lv = (const int*)d_in[3];
    const int*   eg = (const int*)d_in[4];
    float* out = (float*)d_out;

    int N = in_sizes[3];
    int E = in_sizes[4] / 2;

    // workspace: Y (bf16 N*F) | cnt(16: [0..3] level counts, [8] ovf counter)
    //            deg(N) [zeroed with cnt] | ell(8N) | bin(4N) | ovf(OVFCAP int2)
    char* p = (char*)d_ws;
    u16* Y     = (u16*)p;   p += (size_t)N * FDIM * sizeof(u16);
    int* cnt   = (int*)p;   p += 16 * sizeof(int);
    int* deg   = (int*)p;   p += (size_t)N * sizeof(int);
    int* ell   = (int*)p;   p += (size_t)SLOTS * N * sizeof(int);
    int* bin   = (int*)p;   p += (size_t)4 * N * sizeof(int);
    int2* ovf  = (int2*)p;
    int* ovfcnt = cnt + 8;

    int nzero4 = (N + 16) / 4;   // cnt(16) + deg(N), N divisible by 4
    zero_kernel<<<(nzero4 + 255) / 256, 256, 0, stream>>>((int4*)cnt, nzero4);

    int nodeBlocks = (N + 255) / 256;
    int edgeBlocks = (E + 255) / 256;
    fillbin_kernel<<<max(nodeBlocks, edgeBlocks), 256, 0, stream>>>(
        lv, cnt, bin, (const int2*)eg, deg, ell, ovf, ovfcnt, N, E, nodeBlocks);

    int blocksPerLevel = (N + NT - 1) / NT;
    transform_kernel<<<NLEV * blocksPerLevel, 256, 0, stream>>>(
        X, Wg, bg, cnt, bin, Y, N, blocksPerLevel);

    gather_kernel<<<(N + 7) / 8, 256, 0, stream>>>(
        X, (const uint2*)Y, deg, ell, out, N);

    ovf_kernel<<<64, 256, 0, stream>>>(ovf, ovfcnt, (const uint2*)Y, out);
}

// Round 9
// 79.244 us; speedup vs baseline: 1.1341x; 1.0211x over previous
//
#include <hip/hip_runtime.h>
#include <hip/hip_bf16.h>

#define FDIM 128
#define NLEV 4
#define NT   64     // nodes per transform block
#define WPAD 136    // padded row stride (u16): 272B -> 2-way bank alias (free)
#define SLOTS 8     // ELL width; deg>SLOTS goes to overflow list
#define OVFCAP 65536

typedef unsigned int  u32;
typedef unsigned short u16;

typedef __attribute__((ext_vector_type(8))) short short8v;  // 8 bf16 (4 VGPRs)
typedef __attribute__((ext_vector_type(4))) float f32x4;

__device__ __forceinline__ float bf_lo(u32 p) { return __uint_as_float(p << 16); }
__device__ __forceinline__ float bf_hi(u32 p) { return __uint_as_float(p & 0xffff0000u); }
__device__ __forceinline__ u16 f2bf(float f) {
    u32 u = __float_as_uint(f);
    u32 r = (u + 0x7fffu + ((u >> 16) & 1u)) >> 16;   // round-nearest-even
    return (u16)r;
}
__device__ __forceinline__ u32 pack2(float a, float b) {
    return (u32)f2bf(a) | ((u32)f2bf(b) << 16);
}

// ---- K0: fast zero (grid-stride int4) ----
__global__ __launch_bounds__(256) void zero_kernel(int4* __restrict__ p, int n4) {
    int i = blockIdx.x * 256 + threadIdx.x;
    int stride = gridDim.x * 256;
    for (; i < n4; i += stride) p[i] = make_int4(0, 0, 0, 0);
}

// ---- K1: single edge pass builds ELL directly (deg doubles as slot cursor),
//          plus node-binning role on the first nodeBlocks blocks ----
__global__ __launch_bounds__(256) void fillbin_kernel(
    const int* __restrict__ lv, int* __restrict__ cnt, int* __restrict__ bin,
    const int2* __restrict__ edges2, int* __restrict__ deg, int* __restrict__ ell,
    int2* __restrict__ ovf, int* __restrict__ ovfcnt,
    int N, int E, int nodeBlocks)
{
    int t = threadIdx.x;
    int b = blockIdx.x;

    int e = b * 256 + t;
    if (e < E) {
        int2 ed = edges2[e];
        int lo = ed.x, hi = ed.y;
        if (lv[hi] > lv[lo]) {                     // valid <=> lv[hi] > lv[lo]
            int slot = atomicAdd(&deg[hi], 1);
            if (slot < SLOTS) ell[hi * SLOTS + slot] = lo;
            else {
                int oi = atomicAdd(ovfcnt, 1);
                if (oi < OVFCAP) ovf[oi] = make_int2(lo, hi);
            }
        }
    }

    if (b < nodeBlocks) {
        __shared__ int lcnt[NLEV];
        __shared__ int lbase[NLEV];
        if (t < NLEV) lcnt[t] = 0;
        __syncthreads();
        int n = b * 256 + t;
        int l = -1, pos = 0;
        if (n < N) {
            l = lv[n];
            if (l >= 0 && l < NLEV) pos = atomicAdd(&lcnt[l], 1);
            else l = -1;
        }
        __syncthreads();
        if (t < NLEV) lbase[t] = lcnt[t] ? atomicAdd(&cnt[t], lcnt[t]) : 0;
        __syncthreads();
        if (l >= 0) bin[l * N + lbase[l] + pos] = n;
    }
}

// ---- K2 (MFMA): Y[n] = bf16( 0.2*(X[n] @ W[l].T + b[l]) ) for binned nodes ----
// LDS: single Wt buffer (35KB), reused as output staging after the K-loop
// -> 4 blocks/CU (was 2 with a separate 35KB Ot buffer).
__global__ __launch_bounds__(256) void transform_kernel(
    const float* __restrict__ X, const float* __restrict__ Wg,
    const float* __restrict__ bg, const int* __restrict__ cnt,
    const int* __restrict__ bin, u16* __restrict__ Y, int N, int blocksPerLevel)
{
    __shared__ __align__(16) u16 Wt[FDIM][WPAD];  // W[l] bf16 row-major; rows 0..63 reused for output
    __shared__ int nodes_s[NT];

    int b = blockIdx.x;
    int l     = b / blocksPerLevel;
    int chunk = b % blocksPerLevel;
    int m_total = cnt[l];
    int base = chunk * NT;
    if (base >= m_total) return;
    int m = min(NT, m_total - base);
    int t = threadIdx.x;

    if (t < NT) nodes_s[t] = (t < m) ? bin[l * N + base + t] : -1;

    const float4* Wl4 = (const float4*)(Wg + (size_t)l * FDIM * FDIM);
    #pragma unroll
    for (int k = 0; k < 16; ++k) {
        int flat4 = t + k * 256;
        int row = flat4 >> 5;
        int c4  = flat4 & 31;
        float4 v = Wl4[flat4];
        *(uint2*)&Wt[row][c4 * 4] = make_uint2(pack2(v.x, v.y), pack2(v.z, v.w));
    }
    __syncthreads();

    int wid  = t >> 6;
    int lane = t & 63;
    int arow = lane & 15;
    int kgrp = lane >> 4;

    int node = nodes_s[wid * 16 + arow];
    const float* xrow = X + (size_t)(node < 0 ? 0 : node) * FDIM;

    f32x4 acc[8];
    #pragma unroll
    for (int ft = 0; ft < 8; ++ft) acc[ft] = (f32x4){0.f, 0.f, 0.f, 0.f};

    #pragma unroll
    for (int kstep = 0; kstep < 4; ++kstep) {
        int k0 = kstep * 32 + kgrp * 8;
        union { u32 u[4]; short8v v; } au;
        if (node >= 0) {
            float4 x0 = *(const float4*)&xrow[k0];
            float4 x1 = *(const float4*)&xrow[k0 + 4];
            au.u[0] = pack2(x0.x, x0.y); au.u[1] = pack2(x0.z, x0.w);
            au.u[2] = pack2(x1.x, x1.y); au.u[3] = pack2(x1.z, x1.w);
        } else {
            au.u[0] = au.u[1] = au.u[2] = au.u[3] = 0;
        }
        #pragma unroll
        for (int ft = 0; ft < 8; ++ft) {
            short8v bb = *(const short8v*)&Wt[ft * 16 + arow][k0];
            acc[ft] = __builtin_amdgcn_mfma_f32_16x16x32_bf16(au.v, bb, acc[ft], 0, 0, 0);
        }
    }

    __syncthreads();   // all waves done reading Wt -> safe to overwrite rows 0..63

    const float* bl = bg + l * FDIM;
    #pragma unroll
    for (int ft = 0; ft < 8; ++ft) {
        float bv = bl[ft * 16 + arow];
        #pragma unroll
        for (int reg = 0; reg < 4; ++reg) {
            int r = wid * 16 + kgrp * 4 + reg;       // this wave's own rows only
            Wt[r][ft * 16 + arow] = f2bf(0.2f * (acc[ft][reg] + bv));
        }
    }
    __syncthreads();

    #pragma unroll
    for (int k = 0; k < 4; ++k) {
        int flat16 = t + k * 256;
        int row = flat16 >> 4;
        int c   = flat16 & 15;
        int nd = nodes_s[row];
        if (nd >= 0)
            *(uint4*)&Y[(size_t)nd * FDIM + c * 8] = *(const uint4*)&Wt[row][c * 8];
    }
}

// ---- K3: gather from ELL. Half-wave per node; broadcast ELL row, burst Y loads ----
__global__ __launch_bounds__(256) void gather_kernel(
    const float* __restrict__ X, const uint2* __restrict__ Yp,
    const int* __restrict__ deg, const int4* __restrict__ ell4,
    float* __restrict__ out, int N)
{
    int wid  = threadIdx.x >> 6;
    int lane = threadIdx.x & 63;
    int hl = lane >> 5;          // half: 0 or 1
    int sl = lane & 31;          // sub-lane within half
    int node = blockIdx.x * 8 + wid * 2 + hl;
    if (node >= N) return;

    // independent loads up front
    float4 xv = *(const float4*)&X[(size_t)node * FDIM + sl * 4];
    int4 e0 = ell4[node * 2];        // slots 0..3 (same addr across 32 lanes: L1 broadcast)
    int4 e1 = ell4[node * 2 + 1];    // slots 4..7
    int d = deg[node];
    if (d > SLOTS) d = SLOTS;

    int slots[SLOTS] = { e0.x, e0.y, e0.z, e0.w, e1.x, e1.y, e1.z, e1.w };

    // burst: all <=8 Y-row loads in flight at once
    uint2 p[SLOTS];
    #pragma unroll
    for (int j = 0; j < SLOTS; ++j)
        if (j < d) p[j] = Yp[(size_t)slots[j] * (FDIM / 4) + sl];   // 8B/lane, 256B/edge

    float a0 = 0.f, a1 = 0.f, a2 = 0.f, a3 = 0.f;
    #pragma unroll
    for (int j = 0; j < SLOTS; ++j) {
        if (j < d) {
            a0 += bf_lo(p[j].x); a1 += bf_hi(p[j].x);
            a2 += bf_lo(p[j].y); a3 += bf_hi(p[j].y);
        }
    }
    float4 o = make_float4(xv.x + a0, xv.y + a1, xv.z + a2, xv.w + a3);
    *(float4*)&out[(size_t)node * FDIM + sl * 4] = o;
}

// ---- K4: replay overflow edges (deg > SLOTS) with f32 atomics; tiny count ----
__global__ __launch_bounds__(256) void ovf_kernel(
    const int2* __restrict__ ovf, const int* __restrict__ ovfcnt,
    const uint2* __restrict__ Yp, float* __restrict__ out)
{
    int cnt = *ovfcnt;
    if (cnt > OVFCAP) cnt = OVFCAP;
    int hw  = (blockIdx.x * 256 + threadIdx.x) >> 5;   // global half-wave id
    int sl  = threadIdx.x & 31;
    int nhw = gridDim.x * 8;
    for (int i = hw; i < cnt; i += nhw) {
        int2 ed = ovf[i];
        uint2 pv = Yp[(size_t)ed.x * (FDIM / 4) + sl];
        float* dst = out + (size_t)ed.y * FDIM + sl * 4;
        atomicAdd(dst + 0, bf_lo(pv.x));
        atomicAdd(dst + 1, bf_hi(pv.x));
        atomicAdd(dst + 2, bf_lo(pv.y));
        atomicAdd(dst + 3, bf_hi(pv.y));
    }
}

extern "C" void kernel_launch(void* const* d_in, const int* in_sizes, int n_in,
                              void* d_out, int out_size, void* d_ws, size_t ws_size,
                              hipStream_t stream) {
    const float* X  = (const float*)d_in[0];
    const float* Wg = (const float*)d_in[1];
    const float* bg = (const float*)d_in[2];
    const int*   lv = (const int*)d_in[3];
    const int*   eg = (const int*)d_in[4];
    float* out = (float*)d_out;

    int N = in_sizes[3];
    int E = in_sizes[4] / 2;

    // workspace: Y (bf16 N*F) | cnt(16: [0..3] level counts, [8] ovf counter)
    //            deg(N) [zeroed with cnt] | ell(8N) | bin(4N) | ovf(OVFCAP int2)
    char* p = (char*)d_ws;
    u16* Y     = (u16*)p;   p += (size_t)N * FDIM * sizeof(u16);
    int* cnt   = (int*)p;   p += 16 * sizeof(int);
    int* deg   = (int*)p;   p += (size_t)N * sizeof(int);
    int* ell   = (int*)p;   p += (size_t)SLOTS * N * sizeof(int);
    int* bin   = (int*)p;   p += (size_t)4 * N * sizeof(int);
    int2* ovf  = (int2*)p;
    int* ovfcnt = cnt + 8;

    int nzero4 = (N + 16) / 4;   // cnt(16) + deg(N), N divisible by 4
    zero_kernel<<<(nzero4 + 255) / 256, 256, 0, stream>>>((int4*)cnt, nzero4);

    int nodeBlocks = (N + 255) / 256;
    int edgeBlocks = (E + 255) / 256;
    fillbin_kernel<<<max(nodeBlocks, edgeBlocks), 256, 0, stream>>>(
        lv, cnt, bin, (const int2*)eg, deg, ell, ovf, ovfcnt, N, E, nodeBlocks);

    int blocksPerLevel = (N + NT - 1) / NT;
    transform_kernel<<<NLEV * blocksPerLevel, 256, 0, stream>>>(
        X, Wg, bg, cnt, bin, Y, N, blocksPerLevel);

    gather_kernel<<<(N + 7) / 8, 256, 0, stream>>>(
        X, (const uint2*)Y, deg, (const int4*)ell, out, N);

    ovf_kernel<<<64, 256, 0, stream>>>(ovf, ovfcnt, (const uint2*)Y, out);
}